// Round 4
// baseline (297.998 us; speedup 1.0000x reference)
//
#include <hip/hip_runtime.h>
#include <hip/hip_bf16.h>
#include <math.h>

#define NTOK 65536
#define DMODEL 256
#define NEXP 8
#define CAP 65536
#define MAXTILES 520

typedef __bf16 bf16_t;
typedef __bf16 bf16x8 __attribute__((ext_vector_type(8)));
typedef float f32x4 __attribute__((ext_vector_type(4)));

// async global->LDS, 16B per lane. Global addr may be per-lane (gather);
// LDS dest = wave-uniform base + lane*16.
__device__ inline void async16(const void* g, void* l) {
  __builtin_amdgcn_global_load_lds(
      (const __attribute__((address_space(1))) unsigned int*)g,
      (__attribute__((address_space(3))) unsigned int*)l, 16, 0, 0);
}

// Prep: zero counters + transpose gate weights fp32 [E][D] -> [D][E].
__global__ void prep_kernel(const float* __restrict__ wg, float* __restrict__ wgT,
                            int* __restrict__ counts) {
  int t = blockIdx.x * 256 + threadIdx.x;
  if (t < NEXP * DMODEL) wgT[t] = wg[(t & 7) * 256 + (t >> 3)];
  if (blockIdx.x == 0 && threadIdx.x < NEXP) counts[threadIdx.x] = 0;
}

// Cast W1/W2 fp32 [e][k][n] -> bf16 transposed [e][n][k] via 32x32 LDS tile.
__global__ __launch_bounds__(256) void castT_kernel(
    const float* __restrict__ W1, const float* __restrict__ W2,
    bf16_t* __restrict__ w1t, bf16_t* __restrict__ w2t) {
  __shared__ float tile[32][33];
  const int m = blockIdx.z;
  const float* src = (m < 8) ? (W1 + (size_t)m * 65536) : (W2 + (size_t)(m - 8) * 65536);
  bf16_t* dst = (m < 8) ? (w1t + (size_t)m * 65536) : (w2t + (size_t)(m - 8) * 65536);
  const int x0 = blockIdx.x * 32, y0 = blockIdx.y * 32;
  const int tx = threadIdx.x, ty = threadIdx.y;
#pragma unroll
  for (int i = 0; i < 4; ++i)
    tile[ty + i * 8][tx] = src[(size_t)(y0 + ty + i * 8) * 256 + x0 + tx];
  __syncthreads();
#pragma unroll
  for (int i = 0; i < 4; ++i)
    dst[(size_t)(x0 + ty + i * 8) * 256 + y0 + tx] = (bf16_t)tile[tx][ty + i * 8];
}

// Gate v5: 512 blocks x 128 thr; each WAVE owns 64 tokens, wave-private
// double-buffered LDS staging via global_load_lds (16 KB in flight/wave ->
// BW-bound per Little's law). No __syncthreads in the pipeline; explicit
// s_waitcnt vmcnt(N). Deposit-side XOR swizzle (g^(t&7) in the GLOBAL addr)
// spreads LDS banks while read-side order stays lane-uniform -> gate weights
// remain scalar s_loads. Numerics = validated R3 (8-term fp32 chains + fp64).
__global__ __launch_bounds__(128) void gate_kernel(
    const float* __restrict__ x, const float* __restrict__ wgT,
    bf16_t* __restrict__ xb, float* __restrict__ gateval,
    int* __restrict__ counts, int* __restrict__ idxbuf) {
  __shared__ __align__(16) float stage[2][2][2048];  // [wave][buf][64 tok x 32 dims]
  const int th = threadIdx.x;
  const int w = th >> 6, lane = th & 63;
  const int T0 = blockIdx.x * 128 + w * 64;
  const int key = lane & 7;
  const int dtok = lane >> 3;                 // deposit: token-within-instr
  const int dg = (lane & 7) ^ (dtok & 7);     // deposit: swizzled 4-dim group

  auto issue = [&](int c) {
    float* base = &stage[w][c & 1][0];
#pragma unroll
    for (int m = 0; m < 8; ++m)
      async16(x + (size_t)(T0 + m * 8 + dtok) * 256 + c * 32 + dg * 4,
              base + m * 256);
  };

  double acc[8] = {0, 0, 0, 0, 0, 0, 0, 0};
  issue(0);
  issue(1);
#pragma unroll
  for (int c = 0; c < 8; ++c) {
    // outstanding younger than chunk c: stores(c-1)=4 + loads(c+1)=8
    if (c == 0)      asm volatile("s_waitcnt vmcnt(8)" ::: "memory");
    else if (c == 7) asm volatile("s_waitcnt vmcnt(4)" ::: "memory");
    else             asm volatile("s_waitcnt vmcnt(12)" ::: "memory");
    const float* buf = &stage[w][c & 1][0];
    float xg[32];
#pragma unroll
    for (int g = 0; g < 8; ++g) {
      f32x4 v = *(const f32x4*)(buf + lane * 32 + ((g ^ key) * 4));
      xg[g * 4 + 0] = v[0]; xg[g * 4 + 1] = v[1];
      xg[g * 4 + 2] = v[2]; xg[g * 4 + 3] = v[3];
    }
#pragma unroll
    for (int q = 0; q < 4; ++q) {  // xb bf16 write-through
      bf16x8 bv;
#pragma unroll
      for (int j = 0; j < 8; ++j) bv[j] = (bf16_t)xg[q * 8 + j];
      *(bf16x8*)(xb + (size_t)(T0 + lane) * 256 + c * 32 + q * 8) = bv;
    }
#pragma unroll
    for (int e = 0; e < 8; ++e) {
#pragma unroll
      for (int h = 0; h < 4; ++h) {
        float s = 0.f;
#pragma unroll
        for (int j = 0; j < 8; ++j)
          s = fmaf(xg[h * 8 + j], wgT[(c * 32 + h * 8 + j) * 8 + e], s);
        acc[e] += (double)s;
      }
    }
    asm volatile("s_waitcnt lgkmcnt(0)" ::: "memory");  // LDS reads retired
    if (c < 6) issue(c + 2);
  }
  // per-wave softmax + ballot-aggregated bucket scatter
  double m = acc[0]; int bi = 0;
#pragma unroll
  for (int e = 1; e < 8; ++e) if (acc[e] > m) { m = acc[e]; bi = e; }
  float denom = 0.f;
#pragma unroll
  for (int e = 0; e < 8; ++e) denom += __expf((float)(acc[e] - m));
  gateval[T0 + lane] = 1.0f / denom;
#pragma unroll
  for (int e = 0; e < NEXP; ++e) {
    unsigned long long mask = __ballot(bi == e);
    if (mask) {
      int leader = __ffsll(mask) - 1;
      int base = 0;
      if (lane == leader) base = atomicAdd(&counts[e], __popcll(mask));
      base = __shfl(base, leader, 64);
      if (bi == e) {
        int pos = base + (int)__popcll(mask & ((1ull << lane) - 1ull));
        idxbuf[e * CAP + pos] = T0 + lane;
      }
    }
  }
}

// Scan: token bases + device-side tile list (e in bits 0..2, tm in bits 3+).
__global__ void scan_kernel(const int* __restrict__ counts, int* __restrict__ bases,
                            int* __restrict__ tl, int* __restrict__ ntiles) {
  int t = threadIdx.x;
  if (t == 0) {
    int s = 0, n = 0;
    for (int e = 0; e < NEXP; ++e) {
      bases[e] = s; s += counts[e];
      n += (counts[e] + 127) >> 7;
    }
    *ntiles = n;
  }
  if (t < NEXP) {
    int off = 0;
    for (int j = 0; j < t; ++j) off += (counts[j] + 127) >> 7;
    int n = (counts[t] + 127) >> 7;
    for (int k = 0; k < n; ++k) tl[off + k] = t | (k << 3);
  }
}

// GEMM1: h[slot][n] = relu(x[idx[slot]] @ W1[e] + b1[e]), bf16 out.
// Tile-list driven: grid (519, 2); no empty per-expert blocks.
__global__ __launch_bounds__(256) void gemm1_kernel(
    const bf16_t* __restrict__ xb, const bf16_t* __restrict__ w1t,
    const float* __restrict__ b1, const int* __restrict__ counts,
    const int* __restrict__ bases, const int* __restrict__ idxbuf,
    const int* __restrict__ tl, const int* __restrict__ ntiles,
    bf16_t* __restrict__ h) {
  if ((int)blockIdx.x >= *ntiles) return;
  const int tle = tl[blockIdx.x];
  const int e = tle & 7, tm = tle >> 3;
  const int cnt = counts[e];
  const int nt = blockIdx.y;
  const int bse = bases[e];
  __shared__ __align__(16) bf16_t As[128 * 64];
  __shared__ __align__(16) bf16_t Bs[128 * 64];
  __shared__ int sidx[128];
  const int th = threadIdx.x;
  const int ln = th & 63, wv = th >> 6;
  if (th < 128) {
    int r = tm * 128 + th;
    sidx[th] = idxbuf[e * CAP + (r < cnt ? r : cnt - 1)];
  }
  __syncthreads();
  f32x4 acc[4][4] = {};
  const bf16_t* w1e = w1t + (size_t)e * 65536;
  const int wm = (wv & 1) * 64, wn = (wv >> 1) * 64;
  const int lr = ln & 15, lq = ln >> 4;
  for (int kk = 0; kk < 256; kk += 64) {
#pragma unroll
    for (int i = 0; i < 4; ++i) {
      int c = i * 256 + th;               // A: [128 r][8 j]
      int r = c >> 3, j = c & 7;
      async16(xb + (size_t)sidx[r] * 256 + kk + j * 8, &As[(i * 256 + wv * 64) * 8]);
    }
#pragma unroll
    for (int i = 0; i < 4; ++i) {
      int c = i * 256 + th;               // B: [128 n][8 j] from W1t[e][n][k]
      int n = c >> 3, j = c & 7;
      async16(w1e + (size_t)(nt * 128 + n) * 256 + kk + j * 8, &Bs[(i * 256 + wv * 64) * 8]);
    }
    __syncthreads();
#pragma unroll
    for (int kb = 0; kb < 2; ++kb) {
      bf16x8 af[4], bfr[4];
#pragma unroll
      for (int mi = 0; mi < 4; ++mi)
        af[mi] = *(const bf16x8*)&As[(wm + mi * 16 + lr) * 64 + kb * 32 + lq * 8];
#pragma unroll
      for (int ni = 0; ni < 4; ++ni)
        bfr[ni] = *(const bf16x8*)&Bs[(wn + ni * 16 + lr) * 64 + kb * 32 + lq * 8];
#pragma unroll
      for (int mi = 0; mi < 4; ++mi)
#pragma unroll
        for (int ni = 0; ni < 4; ++ni)
          acc[mi][ni] = __builtin_amdgcn_mfma_f32_16x16x32_bf16(af[mi], bfr[ni], acc[mi][ni], 0, 0, 0);
    }
    __syncthreads();
  }
#pragma unroll
  for (int ni = 0; ni < 4; ++ni) {
    int n = nt * 128 + wn + ni * 16 + lr;
    float bias = b1[e * 256 + n];
#pragma unroll
    for (int mi = 0; mi < 4; ++mi) {
#pragma unroll
      for (int r = 0; r < 4; ++r) {
        int rowb = wm + mi * 16 + lq * 4 + r;   // C layout: col=lane&15, row=quad*4+reg
        int row = tm * 128 + rowb;
        if (row < cnt) {
          float v = acc[mi][ni][r] + bias;
          v = v > 0.f ? v : 0.f;
          h[(size_t)(bse + row) * 256 + n] = (bf16_t)v;
        }
      }
    }
  }
}

// GEMM2: out[tok][n] = (h[slot] @ W2[e] + b2[e]) * gate, scattered fp32 store.
__global__ __launch_bounds__(256) void gemm2_kernel(
    const bf16_t* __restrict__ h, const bf16_t* __restrict__ w2t,
    const float* __restrict__ b2, const float* __restrict__ gateval,
    const int* __restrict__ counts, const int* __restrict__ bases,
    const int* __restrict__ idxbuf, const int* __restrict__ tl,
    const int* __restrict__ ntiles, float* __restrict__ out) {
  if ((int)blockIdx.x >= *ntiles) return;
  const int tle = tl[blockIdx.x];
  const int e = tle & 7, tm = tle >> 3;
  const int cnt = counts[e];
  const int nt = blockIdx.y;
  const int bse = bases[e];
  __shared__ __align__(16) bf16_t As[128 * 64];
  __shared__ __align__(16) bf16_t Bs[128 * 64];
  __shared__ int sidx[128];
  __shared__ float sgv[128];
  const int th = threadIdx.x;
  const int ln = th & 63, wv = th >> 6;
  if (th < 128) {
    int r = tm * 128 + th;
    int t = idxbuf[e * CAP + (r < cnt ? r : cnt - 1)];
    sidx[th] = t;
    sgv[th] = gateval[t];
  }
  __syncthreads();
  f32x4 acc[4][4] = {};
  const bf16_t* w2e = w2t + (size_t)e * 65536;
  const int wm = (wv & 1) * 64, wn = (wv >> 1) * 64;
  const int lr = ln & 15, lq = ln >> 4;
  for (int kk = 0; kk < 256; kk += 64) {
#pragma unroll
    for (int i = 0; i < 4; ++i) {
      int c = i * 256 + th;
      int r = c >> 3, j = c & 7;
      int rg = tm * 128 + r; rg = rg < cnt ? rg : cnt - 1;
      async16(h + (size_t)(bse + rg) * 256 + kk + j * 8, &As[(i * 256 + wv * 64) * 8]);
    }
#pragma unroll
    for (int i = 0; i < 4; ++i) {
      int c = i * 256 + th;
      int n = c >> 3, j = c & 7;
      async16(w2e + (size_t)(nt * 128 + n) * 256 + kk + j * 8, &Bs[(i * 256 + wv * 64) * 8]);
    }
    __syncthreads();
#pragma unroll
    for (int kb = 0; kb < 2; ++kb) {
      bf16x8 af[4], bfr[4];
#pragma unroll
      for (int mi = 0; mi < 4; ++mi)
        af[mi] = *(const bf16x8*)&As[(wm + mi * 16 + lr) * 64 + kb * 32 + lq * 8];
#pragma unroll
      for (int ni = 0; ni < 4; ++ni)
        bfr[ni] = *(const bf16x8*)&Bs[(wn + ni * 16 + lr) * 64 + kb * 32 + lq * 8];
#pragma unroll
      for (int mi = 0; mi < 4; ++mi)
#pragma unroll
        for (int ni = 0; ni < 4; ++ni)
          acc[mi][ni] = __builtin_amdgcn_mfma_f32_16x16x32_bf16(af[mi], bfr[ni], acc[mi][ni], 0, 0, 0);
    }
    __syncthreads();
  }
#pragma unroll
  for (int ni = 0; ni < 4; ++ni) {
    int n = nt * 128 + wn + ni * 16 + lr;
    float bias = b2[e * 256 + n];
#pragma unroll
    for (int mi = 0; mi < 4; ++mi) {
#pragma unroll
      for (int r = 0; r < 4; ++r) {
        int rowb = wm + mi * 16 + lq * 4 + r;
        int row = tm * 128 + rowb;
        if (row < cnt) {
          int tok = sidx[rowb];
          out[(size_t)tok * 256 + n] = (acc[mi][ni][r] + bias) * sgv[rowb];
        }
      }
    }
  }
}

extern "C" void kernel_launch(void* const* d_in, const int* in_sizes, int n_in,
                              void* d_out, int out_size, void* d_ws, size_t ws_size,
                              hipStream_t stream) {
  (void)in_sizes; (void)n_in; (void)out_size; (void)ws_size;
  const float* x  = (const float*)d_in[0];
  const float* wg = (const float*)d_in[1];
  const float* W1 = (const float*)d_in[2];
  const float* b1 = (const float*)d_in[3];
  const float* W2 = (const float*)d_in[4];
  const float* b2 = (const float*)d_in[5];
  float* out = (float*)d_out;

  char* ws = (char*)d_ws;
  size_t off = 0;
  auto alloc = [&](size_t bytes) {
    void* p = ws + off;
    off += (bytes + 255) & ~(size_t)255;
    return p;
  };
  bf16_t* xb     = (bf16_t*)alloc((size_t)NTOK * DMODEL * 2);   // 32 MB
  bf16_t* hbuf   = (bf16_t*)alloc((size_t)NTOK * DMODEL * 2);   // 32 MB
  bf16_t* w1t    = (bf16_t*)alloc((size_t)NEXP * 256 * 256 * 2);
  bf16_t* w2t    = (bf16_t*)alloc((size_t)NEXP * 256 * 256 * 2);
  int*    idxbuf = (int*)alloc((size_t)NEXP * CAP * 4);         // 2 MB
  float*  gv     = (float*)alloc((size_t)NTOK * 4);
  float*  wgT    = (float*)alloc((size_t)NEXP * DMODEL * 4);
  int*    tilel  = (int*)alloc((size_t)MAXTILES * 4);
  int*    counts = (int*)alloc(64);
  int*    bases  = (int*)alloc(64);
  int*    ntiles = (int*)alloc(64);

  hipLaunchKernelGGL(prep_kernel, dim3(8), dim3(256), 0, stream, wg, wgT, counts);
  hipLaunchKernelGGL(castT_kernel, dim3(8, 8, 16), dim3(32, 8), 0, stream, W1, W2, w1t, w2t);
  hipLaunchKernelGGL(gate_kernel, dim3(NTOK / 128), dim3(128), 0, stream,
                     x, wgT, xb, gv, counts, idxbuf);
  hipLaunchKernelGGL(scan_kernel, dim3(1), dim3(64), 0, stream, counts, bases, tilel, ntiles);
  hipLaunchKernelGGL(gemm1_kernel, dim3(MAXTILES - 1, 2), dim3(256), 0, stream,
                     xb, w1t, b1, counts, bases, idxbuf, tilel, ntiles, hbuf);
  hipLaunchKernelGGL(gemm2_kernel, dim3(MAXTILES - 1, 2), dim3(256), 0, stream,
                     hbuf, w2t, b2, gv, counts, bases, idxbuf, tilel, ntiles, out);
}

// Round 5
// 226.284 us; speedup vs baseline: 1.3169x; 1.3169x over previous
//
#include <hip/hip_runtime.h>
#include <hip/hip_bf16.h>
#include <math.h>

#define NTOK 65536
#define DMODEL 256
#define NEXP 8
#define CAP 65536
#define MAXTILES 520
#define CSTRIDE 64   // counter spacing in ints (256 B) - one L2 line per expert

typedef __bf16 bf16_t;
typedef __bf16 bf16x8 __attribute__((ext_vector_type(8)));
typedef float f32x4 __attribute__((ext_vector_type(4)));

// async global->LDS, 16B per lane. Global addr may be per-lane (gather);
// LDS dest = wave-uniform base + lane*16.
__device__ inline void async16(const void* g, void* l) {
  __builtin_amdgcn_global_load_lds(
      (const __attribute__((address_space(1))) unsigned int*)g,
      (__attribute__((address_space(3))) unsigned int*)l, 16, 0, 0);
}

// Prep: zero spread counters + transpose gate weights fp32 [E][D] -> [D][E].
__global__ void prep_kernel(const float* __restrict__ wg, float* __restrict__ wgT,
                            int* __restrict__ counts) {
  int t = blockIdx.x * 256 + threadIdx.x;
  if (t < NEXP * DMODEL) wgT[t] = wg[(t & 7) * 256 + (t >> 3)];
  if (t < NEXP * CSTRIDE) counts[t] = 0;
}

// Cast W1/W2 fp32 [e][k][n] -> bf16 transposed [e][n][k] via 32x32 LDS tile.
__global__ __launch_bounds__(256) void castT_kernel(
    const float* __restrict__ W1, const float* __restrict__ W2,
    bf16_t* __restrict__ w1t, bf16_t* __restrict__ w2t) {
  __shared__ float tile[32][33];
  const int m = blockIdx.z;
  const float* src = (m < 8) ? (W1 + (size_t)m * 65536) : (W2 + (size_t)(m - 8) * 65536);
  bf16_t* dst = (m < 8) ? (w1t + (size_t)m * 65536) : (w2t + (size_t)(m - 8) * 65536);
  const int x0 = blockIdx.x * 32, y0 = blockIdx.y * 32;
  const int tx = threadIdx.x, ty = threadIdx.y;
#pragma unroll
  for (int i = 0; i < 4; ++i)
    tile[ty + i * 8][tx] = src[(size_t)(y0 + ty + i * 8) * 256 + x0 + tx];
  __syncthreads();
#pragma unroll
  for (int i = 0; i < 4; ++i)
    dst[(size_t)(x0 + ty + i * 8) * 256 + y0 + tx] = (bf16_t)tile[tx][ty + i * 8];
}

// Gate v6 = R3's v4 streaming (best measured: VGPR 24, 0 conflicts) with the
// scatter tail fixed: counters spread 256 B apart (8 parallel L2 atomic
// queues, not 1) and ONE atomic per (block,expert) issued concurrently from
// lanes 0-7. R1-R4's invariant ~110-147 us floor == 8192 same-line returning
// atomics fully serialized; this cuts the per-line queue 8192 -> 1024 and
// parallelizes 8-wide. Dot-product numerics identical to validated R3.
__global__ __launch_bounds__(512, 4) void gate_kernel(
    const float* __restrict__ x, const float* __restrict__ wgT,
    bf16_t* __restrict__ xb, float* __restrict__ gateval,
    int* __restrict__ counts, int* __restrict__ idxbuf) {
  __shared__ double part[7][64][9];  // +1 pad: 18-word stride, 2-way (free)
  const int lane = threadIdx.x & 63;
  const int seg = __builtin_amdgcn_readfirstlane(threadIdx.x >> 6);  // 0..7
  const int tok = blockIdx.x * 64 + lane;
  const float* xrow = x + (size_t)tok * 256 + seg * 32;
  bf16_t* xbrow = xb + (size_t)tok * 256 + seg * 32;
  const float* wp = wgT + seg * 32 * 8;  // [32 dims][8 experts], uniform
  double acc[8] = {0, 0, 0, 0, 0, 0, 0, 0};
#pragma unroll
  for (int g = 0; g < 4; ++g) {  // 8 dims per group
    float4 a = *(const float4*)(xrow + g * 8);
    float4 b = *(const float4*)(xrow + g * 8 + 4);
    float xv[8] = {a.x, a.y, a.z, a.w, b.x, b.y, b.z, b.w};
    bf16x8 bv;
#pragma unroll
    for (int j = 0; j < 8; ++j) bv[j] = (bf16_t)xv[j];
    *(bf16x8*)(xbrow + g * 8) = bv;
#pragma unroll
    for (int e = 0; e < 8; ++e) {
      float s = 0.f;
#pragma unroll
      for (int j = 0; j < 8; ++j)
        s = fmaf(xv[j], wp[(g * 8 + j) * 8 + e], s);
      acc[e] += (double)s;
    }
  }
  if (seg > 0) {
#pragma unroll
    for (int e = 0; e < 8; ++e) part[seg - 1][lane][e] = acc[e];
  }
  __syncthreads();
  if (seg == 0) {
#pragma unroll
    for (int s2 = 0; s2 < 7; ++s2)
#pragma unroll
      for (int e = 0; e < 8; ++e) acc[e] += part[s2][lane][e];
    double m = acc[0]; int bi = 0;
#pragma unroll
    for (int e = 1; e < 8; ++e) if (acc[e] > m) { m = acc[e]; bi = e; }
    float denom = 0.f;
#pragma unroll
    for (int e = 0; e < 8; ++e) denom += __expf((float)(acc[e] - m));
    gateval[tok] = 1.0f / denom;
    // lane e holds the ballot mask for expert e; lanes 0-7 issue 8
    // concurrent atomics to 8 distinct cachelines.
    unsigned long long mymask = 0;
#pragma unroll
    for (int e = 0; e < NEXP; ++e) {
      unsigned long long mk = __ballot(bi == e);
      if (lane == e) mymask = mk;
    }
    int mybase = 0;
    if (lane < NEXP) mybase = atomicAdd(&counts[lane * CSTRIDE], (int)__popcll(mymask));
#pragma unroll
    for (int e = 0; e < NEXP; ++e) {
      unsigned long long mk = __ballot(bi == e);
      int b = __shfl(mybase, e, 64);
      if (bi == e) {
        int pos = b + (int)__popcll(mk & ((1ull << lane) - 1ull));
        idxbuf[e * CAP + pos] = tok;
      }
    }
  }
}

// Scan: token bases + device-side tile list (e in bits 0..2, tm in bits 3+).
__global__ void scan_kernel(const int* __restrict__ counts, int* __restrict__ bases,
                            int* __restrict__ tl, int* __restrict__ ntiles) {
  int t = threadIdx.x;
  if (t == 0) {
    int s = 0, n = 0;
    for (int e = 0; e < NEXP; ++e) {
      bases[e] = s; s += counts[e * CSTRIDE];
      n += (counts[e * CSTRIDE] + 127) >> 7;
    }
    *ntiles = n;
  }
  if (t < NEXP) {
    int off = 0;
    for (int j = 0; j < t; ++j) off += (counts[j * CSTRIDE] + 127) >> 7;
    int n = (counts[t * CSTRIDE] + 127) >> 7;
    for (int k = 0; k < n; ++k) tl[off + k] = t | (k << 3);
  }
}

// GEMM1: h[slot][n] = relu(x[idx[slot]] @ W1[e] + b1[e]), bf16 out.
// Tile-list driven: grid (519, 2); no empty per-expert blocks.
__global__ __launch_bounds__(256) void gemm1_kernel(
    const bf16_t* __restrict__ xb, const bf16_t* __restrict__ w1t,
    const float* __restrict__ b1, const int* __restrict__ counts,
    const int* __restrict__ bases, const int* __restrict__ idxbuf,
    const int* __restrict__ tl, const int* __restrict__ ntiles,
    bf16_t* __restrict__ h) {
  if ((int)blockIdx.x >= *ntiles) return;
  const int tle = tl[blockIdx.x];
  const int e = tle & 7, tm = tle >> 3;
  const int cnt = counts[e * CSTRIDE];
  const int nt = blockIdx.y;
  const int bse = bases[e];
  __shared__ __align__(16) bf16_t As[128 * 64];
  __shared__ __align__(16) bf16_t Bs[128 * 64];
  __shared__ int sidx[128];
  const int th = threadIdx.x;
  const int ln = th & 63, wv = th >> 6;
  if (th < 128) {
    int r = tm * 128 + th;
    sidx[th] = idxbuf[e * CAP + (r < cnt ? r : cnt - 1)];
  }
  __syncthreads();
  f32x4 acc[4][4] = {};
  const bf16_t* w1e = w1t + (size_t)e * 65536;
  const int wm = (wv & 1) * 64, wn = (wv >> 1) * 64;
  const int lr = ln & 15, lq = ln >> 4;
  for (int kk = 0; kk < 256; kk += 64) {
#pragma unroll
    for (int i = 0; i < 4; ++i) {
      int c = i * 256 + th;               // A: [128 r][8 j]
      int r = c >> 3, j = c & 7;
      async16(xb + (size_t)sidx[r] * 256 + kk + j * 8, &As[(i * 256 + wv * 64) * 8]);
    }
#pragma unroll
    for (int i = 0; i < 4; ++i) {
      int c = i * 256 + th;               // B: [128 n][8 j] from W1t[e][n][k]
      int n = c >> 3, j = c & 7;
      async16(w1e + (size_t)(nt * 128 + n) * 256 + kk + j * 8, &Bs[(i * 256 + wv * 64) * 8]);
    }
    __syncthreads();
#pragma unroll
    for (int kb = 0; kb < 2; ++kb) {
      bf16x8 af[4], bfr[4];
#pragma unroll
      for (int mi = 0; mi < 4; ++mi)
        af[mi] = *(const bf16x8*)&As[(wm + mi * 16 + lr) * 64 + kb * 32 + lq * 8];
#pragma unroll
      for (int ni = 0; ni < 4; ++ni)
        bfr[ni] = *(const bf16x8*)&Bs[(wn + ni * 16 + lr) * 64 + kb * 32 + lq * 8];
#pragma unroll
      for (int mi = 0; mi < 4; ++mi)
#pragma unroll
        for (int ni = 0; ni < 4; ++ni)
          acc[mi][ni] = __builtin_amdgcn_mfma_f32_16x16x32_bf16(af[mi], bfr[ni], acc[mi][ni], 0, 0, 0);
    }
    __syncthreads();
  }
#pragma unroll
  for (int ni = 0; ni < 4; ++ni) {
    int n = nt * 128 + wn + ni * 16 + lr;
    float bias = b1[e * 256 + n];
#pragma unroll
    for (int mi = 0; mi < 4; ++mi) {
#pragma unroll
      for (int r = 0; r < 4; ++r) {
        int rowb = wm + mi * 16 + lq * 4 + r;   // C layout: col=lane&15, row=quad*4+reg
        int row = tm * 128 + rowb;
        if (row < cnt) {
          float v = acc[mi][ni][r] + bias;
          v = v > 0.f ? v : 0.f;
          h[(size_t)(bse + row) * 256 + n] = (bf16_t)v;
        }
      }
    }
  }
}

// GEMM2: out[tok][n] = (h[slot] @ W2[e] + b2[e]) * gate, scattered fp32 store.
__global__ __launch_bounds__(256) void gemm2_kernel(
    const bf16_t* __restrict__ h, const bf16_t* __restrict__ w2t,
    const float* __restrict__ b2, const float* __restrict__ gateval,
    const int* __restrict__ counts, const int* __restrict__ bases,
    const int* __restrict__ idxbuf, const int* __restrict__ tl,
    const int* __restrict__ ntiles, float* __restrict__ out) {
  if ((int)blockIdx.x >= *ntiles) return;
  const int tle = tl[blockIdx.x];
  const int e = tle & 7, tm = tle >> 3;
  const int cnt = counts[e * CSTRIDE];
  const int nt = blockIdx.y;
  const int bse = bases[e];
  __shared__ __align__(16) bf16_t As[128 * 64];
  __shared__ __align__(16) bf16_t Bs[128 * 64];
  __shared__ int sidx[128];
  __shared__ float sgv[128];
  const int th = threadIdx.x;
  const int ln = th & 63, wv = th >> 6;
  if (th < 128) {
    int r = tm * 128 + th;
    int t = idxbuf[e * CAP + (r < cnt ? r : cnt - 1)];
    sidx[th] = t;
    sgv[th] = gateval[t];
  }
  __syncthreads();
  f32x4 acc[4][4] = {};
  const bf16_t* w2e = w2t + (size_t)e * 65536;
  const int wm = (wv & 1) * 64, wn = (wv >> 1) * 64;
  const int lr = ln & 15, lq = ln >> 4;
  for (int kk = 0; kk < 256; kk += 64) {
#pragma unroll
    for (int i = 0; i < 4; ++i) {
      int c = i * 256 + th;
      int r = c >> 3, j = c & 7;
      int rg = tm * 128 + r; rg = rg < cnt ? rg : cnt - 1;
      async16(h + (size_t)(bse + rg) * 256 + kk + j * 8, &As[(i * 256 + wv * 64) * 8]);
    }
#pragma unroll
    for (int i = 0; i < 4; ++i) {
      int c = i * 256 + th;
      int n = c >> 3, j = c & 7;
      async16(w2e + (size_t)(nt * 128 + n) * 256 + kk + j * 8, &Bs[(i * 256 + wv * 64) * 8]);
    }
    __syncthreads();
#pragma unroll
    for (int kb = 0; kb < 2; ++kb) {
      bf16x8 af[4], bfr[4];
#pragma unroll
      for (int mi = 0; mi < 4; ++mi)
        af[mi] = *(const bf16x8*)&As[(wm + mi * 16 + lr) * 64 + kb * 32 + lq * 8];
#pragma unroll
      for (int ni = 0; ni < 4; ++ni)
        bfr[ni] = *(const bf16x8*)&Bs[(wn + ni * 16 + lr) * 64 + kb * 32 + lq * 8];
#pragma unroll
      for (int mi = 0; mi < 4; ++mi)
#pragma unroll
        for (int ni = 0; ni < 4; ++ni)
          acc[mi][ni] = __builtin_amdgcn_mfma_f32_16x16x32_bf16(af[mi], bfr[ni], acc[mi][ni], 0, 0, 0);
    }
    __syncthreads();
  }
#pragma unroll
  for (int ni = 0; ni < 4; ++ni) {
    int n = nt * 128 + wn + ni * 16 + lr;
    float bias = b2[e * 256 + n];
#pragma unroll
    for (int mi = 0; mi < 4; ++mi) {
#pragma unroll
      for (int r = 0; r < 4; ++r) {
        int rowb = wm + mi * 16 + lq * 4 + r;
        int row = tm * 128 + rowb;
        if (row < cnt) {
          int tok = sidx[rowb];
          out[(size_t)tok * 256 + n] = (acc[mi][ni][r] + bias) * sgv[rowb];
        }
      }
    }
  }
}

extern "C" void kernel_launch(void* const* d_in, const int* in_sizes, int n_in,
                              void* d_out, int out_size, void* d_ws, size_t ws_size,
                              hipStream_t stream) {
  (void)in_sizes; (void)n_in; (void)out_size; (void)ws_size;
  const float* x  = (const float*)d_in[0];
  const float* wg = (const float*)d_in[1];
  const float* W1 = (const float*)d_in[2];
  const float* b1 = (const float*)d_in[3];
  const float* W2 = (const float*)d_in[4];
  const float* b2 = (const float*)d_in[5];
  float* out = (float*)d_out;

  char* ws = (char*)d_ws;
  size_t off = 0;
  auto alloc = [&](size_t bytes) {
    void* p = ws + off;
    off += (bytes + 255) & ~(size_t)255;
    return p;
  };
  bf16_t* xb     = (bf16_t*)alloc((size_t)NTOK * DMODEL * 2);   // 32 MB
  bf16_t* hbuf   = (bf16_t*)alloc((size_t)NTOK * DMODEL * 2);   // 32 MB
  bf16_t* w1t    = (bf16_t*)alloc((size_t)NEXP * 256 * 256 * 2);
  bf16_t* w2t    = (bf16_t*)alloc((size_t)NEXP * 256 * 256 * 2);
  int*    idxbuf = (int*)alloc((size_t)NEXP * CAP * 4);         // 2 MB
  float*  gv     = (float*)alloc((size_t)NTOK * 4);
  float*  wgT    = (float*)alloc((size_t)NEXP * DMODEL * 4);
  int*    tilel  = (int*)alloc((size_t)MAXTILES * 4);
  int*    counts = (int*)alloc((size_t)NEXP * CSTRIDE * 4);     // 256B-spread
  int*    bases  = (int*)alloc(64);
  int*    ntiles = (int*)alloc(64);

  hipLaunchKernelGGL(prep_kernel, dim3(8), dim3(256), 0, stream, wg, wgT, counts);
  hipLaunchKernelGGL(castT_kernel, dim3(8, 8, 16), dim3(32, 8), 0, stream, W1, W2, w1t, w2t);
  hipLaunchKernelGGL(gate_kernel, dim3(NTOK / 64), dim3(512), 0, stream,
                     x, wgT, xb, gv, counts, idxbuf);
  hipLaunchKernelGGL(scan_kernel, dim3(1), dim3(64), 0, stream, counts, bases, tilel, ntiles);
  hipLaunchKernelGGL(gemm1_kernel, dim3(MAXTILES - 1, 2), dim3(256), 0, stream,
                     xb, w1t, b1, counts, bases, idxbuf, tilel, ntiles, hbuf);
  hipLaunchKernelGGL(gemm2_kernel, dim3(MAXTILES - 1, 2), dim3(256), 0, stream,
                     hbuf, w2t, b2, gv, counts, bases, idxbuf, tilel, ntiles, out);
}